// Round 9
// baseline (1967.770 us; speedup 1.0000x reference)
//
#include <hip/hip_runtime.h>
#include <stdint.h>

// ---- problem constants (from reference) ----
#define N_NODES 16000
#define MPAD_   16128   // N_NODES padded to multiple of 256 for the 256^2 GEMM
#define B_      32
#define NPG_    500
#define E_      256000
#define F_      1024
#define OD_     128
#define DD_     80
#define TD_     32
#define NH_     4
#define DH_     8
#define DFF_    128
#define LSUB_   128
#define MAXLEN_ 512
#define EPS_    1e-5f
#define SLOPE_  0.01f

typedef __bf16 bf16x8 __attribute__((ext_vector_type(8)));
typedef float  f32x4  __attribute__((ext_vector_type(4)));

__device__ __forceinline__ float leaky(float v) { return v >= 0.f ? v : SLOPE_ * v; }

__device__ __forceinline__ unsigned short f2bf(float f) {
  unsigned u = __float_as_uint(f);
  u += 0x7FFFu + ((u >> 16) & 1u);   // RNE
  return (unsigned short)(u >> 16);
}
__device__ __forceinline__ float bf2f(unsigned short u) {
  return __uint_as_float((unsigned)u << 16);
}
// packed-bf16 dword -> two floats (no ushort extraction)
__device__ __forceinline__ float bflo(unsigned u) { return __uint_as_float(u << 16); }
__device__ __forceinline__ float bfhi(unsigned u) { return __uint_as_float(u & 0xffff0000u); }

__device__ __forceinline__ void gld_lds16(const void* g, void* l) {
  __builtin_amdgcn_global_load_lds(
      (const __attribute__((address_space(1))) unsigned int*)g,
      (__attribute__((address_space(3))) unsigned int*)l, 16, 0, 0);
}

// ---- prep: fp32->bf16 for {x0,x1,w0,w1} + zero cnt/pooled; grid (1024, 5) ----
__global__ void k_prep(const float* __restrict__ x0, const float* __restrict__ x1,
                       const float* __restrict__ w0, const float* __restrict__ w1,
                       unsigned short* __restrict__ xb0, unsigned short* __restrict__ xb1,
                       unsigned short* __restrict__ wb0, unsigned short* __restrict__ wb1,
                       int* __restrict__ cnt, float* __restrict__ pooled) {
  const int y = blockIdx.y;
  int i = blockIdx.x * 256 + threadIdx.x;
  const int stride = gridDim.x * 256;
  if (y == 4) {
    int4 z = make_int4(0, 0, 0, 0);
    for (int idx = i; idx < (2 * N_NODES) / 4; idx += stride) ((int4*)cnt)[idx] = z;
    float4 zf = {0.f, 0.f, 0.f, 0.f};
    for (int idx = i; idx < (2 * B_ * F_) / 4; idx += stride) ((float4*)pooled)[idx] = zf;
    return;
  }
  const float* in = (y == 0) ? x0 : (y == 1) ? x1 : (y == 2) ? w0 : w1;
  unsigned short* out = (y == 0) ? xb0 : (y == 1) ? xb1 : (y == 2) ? wb0 : wb1;
  const int n4 = (y < 2) ? (N_NODES * F_ / 4) : (F_ * F_ / 4);
  for (; i < n4; i += stride) {
    float4 v = ((const float4*)in)[i];
    ushort4 o;
    o.x = f2bf(v.x); o.y = f2bf(v.y); o.z = f2bf(v.z); o.w = f2bf(v.w);
    ((ushort4*)out)[i] = o;
  }
}

// ---- degree histogram over dst (grid.y = graph); runs BEFORE gemm now ----
__global__ void k_hist(const int* __restrict__ ei0, const int* __restrict__ ei1,
                       int* __restrict__ cnt, int e, int n) {
  const int g = blockIdx.y;
  const int* dst = (g ? ei1 : ei0) + e;
  int i = blockIdx.x * 256 + threadIdx.x;
  if (i < e) atomicAdd(&cnt[g * n + dst[i]], 1);
}

// ---- 256x256 8-phase bf16 MFMA GEMM (+ scan rider blocks x==252).
// R8 accounting: ~560us lives in thin launches below top-5; consolidation
// round. Scan (needs hist, which now precedes gemm) rides as 2 extra blocks
// so it costs no launch. ----
#define LDSA(bf, ks, row) (*(const bf16x8*)&lds[(bf)*16384 + (ks)*8192 + (row)*32 + rs])
#define LDSB(bf, ks, row) (*(const bf16x8*)&lds[32768 + (bf)*16384 + (ks)*8192 + (row)*32 + rs])
#define STG_A(bf, R, kti) do { \
  gld_lds16(&Ag[(size_t)(mBase + (R) + r4) * 1024 + (kti) * 64 + c4],      &lds[(bf)*16384 + (R)*32 + t*8]); \
  gld_lds16(&Ag[(size_t)(mBase + (R) + r4) * 1024 + (kti) * 64 + 32 + c4], &lds[(bf)*16384 + 8192 + (R)*32 + t*8]); \
} while (0)
#define STG_B(bf, R, kti) do { \
  gld_lds16(&Bg[(size_t)(nBase + (R) + r4) * 1024 + (kti) * 64 + c4],      &lds[32768 + (bf)*16384 + (R)*32 + t*8]); \
  gld_lds16(&Bg[(size_t)(nBase + (R) + r4) * 1024 + (kti) * 64 + 32 + c4], &lds[32768 + (bf)*16384 + 8192 + (R)*32 + t*8]); \
} while (0)
#define RD_Q0(bf) do { \
  _Pragma("unroll") for (int mi = 0; mi < 4; ++mi) \
  _Pragma("unroll") for (int ks = 0; ks < 2; ++ks) \
    aLo[mi][ks] = LDSA(bf, ks, wrow * 128 + mi * 16 + l15); \
  _Pragma("unroll") for (int ni = 0; ni < 2; ++ni) \
  _Pragma("unroll") for (int ks = 0; ks < 2; ++ks) \
    bLo[ni][ks] = LDSB(bf, ks, wcol * 64 + ni * 16 + l15); \
} while (0)
#define RD_BHI(bf) do { \
  _Pragma("unroll") for (int ni = 0; ni < 2; ++ni) \
  _Pragma("unroll") for (int ks = 0; ks < 2; ++ks) \
    bHi[ni][ks] = LDSB(bf, ks, wcol * 64 + (2 + ni) * 16 + l15); \
} while (0)
#define RD_AHI(bf) do { \
  _Pragma("unroll") for (int mi = 0; mi < 4; ++mi) \
  _Pragma("unroll") for (int ks = 0; ks < 2; ++ks) \
    aHi[mi][ks] = LDSA(bf, ks, wrow * 128 + (4 + mi) * 16 + l15); \
} while (0)
#define MM_Q0() do { __builtin_amdgcn_s_setprio(1); \
  _Pragma("unroll") for (int mi = 0; mi < 4; ++mi) \
  _Pragma("unroll") for (int ni = 0; ni < 2; ++ni) \
  _Pragma("unroll") for (int ks = 0; ks < 2; ++ks) \
    acc[mi][ni] = __builtin_amdgcn_mfma_f32_16x16x32_bf16(aLo[mi][ks], bLo[ni][ks], acc[mi][ni], 0, 0, 0); \
  __builtin_amdgcn_s_setprio(0); } while (0)
#define MM_Q1() do { __builtin_amdgcn_s_setprio(1); \
  _Pragma("unroll") for (int mi = 0; mi < 4; ++mi) \
  _Pragma("unroll") for (int ni = 0; ni < 2; ++ni) \
  _Pragma("unroll") for (int ks = 0; ks < 2; ++ks) \
    acc[mi][2 + ni] = __builtin_amdgcn_mfma_f32_16x16x32_bf16(aLo[mi][ks], bHi[ni][ks], acc[mi][2 + ni], 0, 0, 0); \
  __builtin_amdgcn_s_setprio(0); } while (0)
#define MM_Q3() do { __builtin_amdgcn_s_setprio(1); \
  _Pragma("unroll") for (int mi = 0; mi < 4; ++mi) \
  _Pragma("unroll") for (int ni = 0; ni < 2; ++ni) \
  _Pragma("unroll") for (int ks = 0; ks < 2; ++ks) \
    acc[4 + mi][2 + ni] = __builtin_amdgcn_mfma_f32_16x16x32_bf16(aHi[mi][ks], bHi[ni][ks], acc[4 + mi][2 + ni], 0, 0, 0); \
  __builtin_amdgcn_s_setprio(0); } while (0)
#define MM_Q2() do { __builtin_amdgcn_s_setprio(1); \
  _Pragma("unroll") for (int mi = 0; mi < 4; ++mi) \
  _Pragma("unroll") for (int ni = 0; ni < 2; ++ni) \
  _Pragma("unroll") for (int ks = 0; ks < 2; ++ks) \
    acc[4 + mi][ni] = __builtin_amdgcn_mfma_f32_16x16x32_bf16(aHi[mi][ks], bLo[ni][ks], acc[4 + mi][ni], 0, 0, 0); \
  __builtin_amdgcn_s_setprio(0); } while (0)
#define BAR() do { __builtin_amdgcn_sched_barrier(0); __builtin_amdgcn_s_barrier(); \
                   __builtin_amdgcn_sched_barrier(0); } while (0)
#define LGKM0() do { asm volatile("s_waitcnt lgkmcnt(0)" ::: "memory"); \
                     __builtin_amdgcn_sched_barrier(0); } while (0)
#define VM4() do { asm volatile("s_waitcnt vmcnt(4)" ::: "memory"); } while (0)
#define VM0() do { asm volatile("s_waitcnt vmcnt(0)" ::: "memory"); } while (0)

__global__ __launch_bounds__(512, 2) void k_gemm256(const unsigned short* __restrict__ Ag,
                                                    const unsigned short* __restrict__ Bg,
                                                    unsigned short* __restrict__ Cg,
                                                    const int* __restrict__ cnt_all,
                                                    int* __restrict__ rowstart_all,
                                                    int* __restrict__ cursor_all,
                                                    float* __restrict__ dinv_all) {
  __shared__ short lds[65536];   // 128 KiB: A [2][2][256][32] | B at +32768
  // ---- scan rider: block x==252 per graph does the exclusive scan ----
  if (blockIdx.x == 252) {
    const int g2 = blockIdx.z;
    const int* cnt = cnt_all + g2 * N_NODES;
    int* rowstart = rowstart_all + g2 * (N_NODES + 1);
    int* cursor   = cursor_all + g2 * N_NODES;
    float* dinvp  = dinv_all + g2 * N_NODES;
    int* ipart = (int*)lds;           // [512]
    int* ibase = ipart + 512;         // [513]
    const int tt = threadIdx.x;       // 512
    const int CH = 32;                // 512*32 >= 16000
    int s = 0;
    for (int j2 = 0; j2 < CH; ++j2) {
      int idx = tt * CH + j2;
      if (idx < N_NODES) s += cnt[idx];
    }
    ipart[tt] = s;
    __syncthreads();
    if (tt == 0) {
      int a = 0;
      for (int i2 = 0; i2 < 512; ++i2) { ibase[i2] = a; a += ipart[i2]; }
      ibase[512] = a;
    }
    __syncthreads();
    int a = ibase[tt];
    for (int j2 = 0; j2 < CH; ++j2) {
      int idx = tt * CH + j2;
      if (idx < N_NODES) {
        int c = cnt[idx];
        rowstart[idx] = a; cursor[idx] = a; a += c;
        dinvp[idx] = rsqrtf((float)c + 1.0f);
      }
    }
    if (tt == 0) rowstart[N_NODES] = ibase[512];
    return;
  }
  const int j  = blockIdx.x;     // 0..251
  const int x8 = j & 7;          // stable XCD id under round-robin dispatch
  const int chunk = (x8 < 4) ? x8 * 32 : 128 + (x8 - 4) * 31;  // bijective (m204)
  const int pos = chunk + (j >> 3);
  const int mb = pos >> 2, nb = pos & 3;   // nb fastest within XCD chunk
  const size_t g = blockIdx.z;
  Ag += g * (size_t)MPAD_ * 1024;
  Bg += g * (size_t)1024 * 1024;
  Cg += g * (size_t)MPAD_ * 1024;
  const int t = threadIdx.x;
  const int lane = t & 63, wave = t >> 6;
  const int wrow = wave >> 2, wcol = wave & 3;
  const int quad = lane >> 4, l15 = lane & 15;
  const int mBase = mb * 256, nBase = nb * 256;
  const int r4 = t >> 2;                                // 0..127 staging row
  const int c4 = (((t & 3) - ((t >> 3) & 3)) & 3) * 8;  // source chunk swizzle
  const int rs = ((quad + (l15 >> 1)) & 3) * 8;         // read slot swizzle

  f32x4 acc[8][4];
  f32x4 zero = {0.f, 0.f, 0.f, 0.f};
#pragma unroll
  for (int i = 0; i < 8; ++i)
#pragma unroll
    for (int jn = 0; jn < 4; ++jn) acc[i][jn] = zero;

  bf16x8 aLo[4][2], aHi[4][2], bLo[2][2], bHi[2][2];

  // prologue: T0 fully into buf0; B halves of T1 into buf1
  STG_A(0, 0, 0); STG_A(0, 128, 0); STG_B(0, 0, 0); STG_B(0, 128, 0);
  STG_B(1, 0, 1); STG_B(1, 128, 1);
  VM4();   // T0's 8 loads landed (leaves B(1) pair in flight)
  BAR();

  for (int kt = 0; kt < 16; kt += 2) {
    const bool s2 = (kt + 2) < 16;
    const bool s3 = (kt + 3) < 16;
    RD_Q0(0);
    STG_A(1, 0, kt + 1);
    BAR(); LGKM0(); MM_Q0(); BAR();
    RD_BHI(0);
    STG_A(1, 128, kt + 1);
    BAR(); LGKM0(); MM_Q1(); BAR();
    RD_AHI(0);
    if (s2) STG_B(0, 0, kt + 2);
    BAR(); LGKM0(); MM_Q3(); BAR();
    if (s2) { STG_B(0, 128, kt + 2); VM4(); } else VM0();
    BAR(); MM_Q2(); BAR();
    RD_Q0(1);
    if (s2) STG_A(0, 0, kt + 2);
    BAR(); LGKM0(); MM_Q0(); BAR();
    RD_BHI(1);
    if (s2) STG_A(0, 128, kt + 2);
    BAR(); LGKM0(); MM_Q1(); BAR();
    RD_AHI(1);
    if (s3) STG_B(1, 0, kt + 3);
    BAR(); LGKM0(); MM_Q3(); BAR();
    if (s3) { STG_B(1, 128, kt + 3); VM4(); }
    BAR(); MM_Q2(); BAR();
  }

#pragma unroll
  for (int mi = 0; mi < 8; ++mi)
#pragma unroll
    for (int ni = 0; ni < 4; ++ni)
#pragma unroll
      for (int r = 0; r < 4; ++r) {
        int grow = mBase + wrow * 128 + mi * 16 + quad * 4 + r;
        int gcol = nBase + wcol * 64 + ni * 16 + l15;
        Cg[(size_t)grow * 1024 + gcol] = f2bf(acc[mi][ni][r]);
      }
}

// ---- scatter edges to CSR, fused record {src, weight-bits} (grid.y = graph) ----
__global__ void k_scatter(const int* __restrict__ ei0, const int* __restrict__ ei1,
                          const float* __restrict__ dinv_all, int* __restrict__ cursor_all,
                          int2* __restrict__ csre_all, int e, int n) {
  const int g = blockIdx.y;
  const int* ei = g ? ei1 : ei0;
  int i = blockIdx.x * 256 + threadIdx.x;
  if (i < e) {
    int s = ei[i], d = ei[e + i];
    int p = atomicAdd(&cursor_all[g * n + d], 1);
    float w = dinv_all[g * n + s] * dinv_all[g * n + d];
    csre_all[(size_t)g * e + p] = make_int2(s, __float_as_int(w));
  }
}

// ---- sliced CSR gather + fused mean-pool epilogue (unchanged from R8) ----
__global__ __launch_bounds__(256) void k_gather(const uint4* __restrict__ h8_all,
                                                const float* __restrict__ dinv_all,
                                                const int* __restrict__ rowstart_all,
                                                const int2* __restrict__ csre_all,
                                                const float* __restrict__ bias0,
                                                const float* __restrict__ bias1,
                                                float* __restrict__ pooled) {
  const int g = blockIdx.z;
  const uint4* h8 = h8_all + (size_t)g * MPAD_ * 128;   // 128 uint4 per row
  const float* dinv = dinv_all + (size_t)g * N_NODES;
  const int* rowstart = rowstart_all + (size_t)g * (N_NODES + 1);
  const int2* csre = csre_all + (size_t)g * E_;
  const int sl = blockIdx.x;                    // feature slice 0..7
  const int t = threadIdx.x;
  const int wv = t >> 6, lane = t & 63;
  const int qtr = lane >> 4, l16 = lane & 15;
  const int i = blockIdx.y * 16 + wv * 4 + qtr; // dst node (exactly 16000)
  const int fo8 = sl * 16 + l16;                // uint4 index within row
  const float di = dinv[i];
  const float selfw = di * di;
  uint4 sv = h8[(size_t)i * 128 + fo8];
  float a0 = bflo(sv.x) * selfw, a1 = bfhi(sv.x) * selfw;
  float a2 = bflo(sv.y) * selfw, a3 = bfhi(sv.y) * selfw;
  float a4 = bflo(sv.z) * selfw, a5 = bfhi(sv.z) * selfw;
  float a6 = bflo(sv.w) * selfw, a7 = bfhi(sv.w) * selfw;
  int j = rowstart[i];
  const int end = rowstart[i + 1];
  for (; j + 2 <= end; j += 2) {
    int2 e0 = csre[j], e1 = csre[j + 1];
    uint4 v0 = h8[(size_t)e0.x * 128 + fo8];
    uint4 v1 = h8[(size_t)e1.x * 128 + fo8];
    float w0 = __int_as_float(e0.y), w1 = __int_as_float(e1.y);
    a0 += bflo(v0.x) * w0 + bflo(v1.x) * w1;
    a1 += bfhi(v0.x) * w0 + bfhi(v1.x) * w1;
    a2 += bflo(v0.y) * w0 + bflo(v1.y) * w1;
    a3 += bfhi(v0.y) * w0 + bfhi(v1.y) * w1;
    a4 += bflo(v0.z) * w0 + bflo(v1.z) * w1;
    a5 += bfhi(v0.z) * w0 + bfhi(v1.z) * w1;
    a6 += bflo(v0.w) * w0 + bflo(v1.w) * w1;
    a7 += bfhi(v0.w) * w0 + bfhi(v1.w) * w1;
  }
  if (j < end) {
    int2 e0 = csre[j];
    uint4 v0 = h8[(size_t)e0.x * 128 + fo8];
    float w0 = __int_as_float(e0.y);
    a0 += bflo(v0.x) * w0; a1 += bfhi(v0.x) * w0;
    a2 += bflo(v0.y) * w0; a3 += bfhi(v0.y) * w0;
    a4 += bflo(v0.z) * w0; a5 += bfhi(v0.z) * w0;
    a6 += bflo(v0.w) * w0; a7 += bfhi(v0.w) * w0;
  }
  // ---- fused mean-pool epilogue ----
  const float* gbias = g ? bias1 : bias0;
  const int f0 = fo8 * 8;                       // first feat of this lane
  float pk[8];
  pk[0] = leaky(a0 + gbias[f0 + 0]); pk[1] = leaky(a1 + gbias[f0 + 1]);
  pk[2] = leaky(a2 + gbias[f0 + 2]); pk[3] = leaky(a3 + gbias[f0 + 3]);
  pk[4] = leaky(a4 + gbias[f0 + 4]); pk[5] = leaky(a5 + gbias[f0 + 5]);
  pk[6] = leaky(a6 + gbias[f0 + 6]); pk[7] = leaky(a7 + gbias[f0 + 7]);
  __shared__ float sacc[4][16][8];
  const int i0 = blockIdx.y * 16;
  const int b0 = i0 / NPG_, b1 = (i0 + 15) / NPG_;
  const int myb = i / NPG_;
  const int npass = (b0 == b1) ? 1 : 2;         // block-uniform
  for (int pass = 0; pass < npass; ++pass) {
    const int bt = pass ? b1 : b0;
    float v[8];
#pragma unroll
    for (int k = 0; k < 8; ++k) {
      float x = (myb == bt) ? pk[k] : 0.f;
      x += __shfl_xor(x, 16);                   // sum adjacent quarters
      x += __shfl_xor(x, 32);                   // -> all 4 quarter-nodes
      v[k] = x;
    }
    if (qtr == 0) {
#pragma unroll
      for (int k = 0; k < 8; ++k) sacc[wv][l16][k] = v[k];
    }
    __syncthreads();
    if (t < 128) {
      const int li = t >> 3, kk = t & 7;
      float tot = sacc[0][li][kk] + sacc[1][li][kk] + sacc[2][li][kk] + sacc[3][li][kk];
      atomicAdd(&pooled[(((size_t)g * B_ + bt) << 10) + sl * 128 + t], tot);
    }
    __syncthreads();
  }
}

// ---- k_former: pack + totlen + 2 transformer layers + masked-mean + fc +
// final, all in ONE kernel. One block per batch element (32 blocks, 1024
// threads). xt[512][33] (padded: per-lane row reads spread banks) lives in
// LDS across all phases. K/V per head staged on the fly from xt; post runs
// in 32-row chunks over a reused 32KB scratch. All __syncthreads are
// block-uniform (per-thread predicates only; c0>=L break is uniform). ----
__global__ __launch_bounds__(1024, 1) void k_former(
    const float* __restrict__ m0, const float* __restrict__ m1,
    const float* __restrict__ m2, const float* __restrict__ m3,
    const int* __restrict__ l0, const int* __restrict__ l1,
    const int* __restrict__ l2, const int* __restrict__ l3,
    const float* __restrict__ rw, const float* __restrict__ rb,
    const float* __restrict__ attn_in_w, const float* __restrict__ attn_in_b,
    const float* __restrict__ attn_out_w, const float* __restrict__ attn_out_b,
    const float* __restrict__ ln1_w, const float* __restrict__ ln1_b,
    const float* __restrict__ ln2_w, const float* __restrict__ ln2_b,
    const float* __restrict__ ff1_w, const float* __restrict__ ff1_b,
    const float* __restrict__ ff2_w, const float* __restrict__ ff2_b,
    const float* __restrict__ pooled,
    const float* __restrict__ fcw0, const float* __restrict__ fcw1,
    const float* __restrict__ fcb0, const float* __restrict__ fcb1,
    const float* __restrict__ fw, const float* __restrict__ fb,
    float* __restrict__ out) {
  __shared__ float xt[512 * 33];   // 67.5 KB, padded rows
  __shared__ float scr[8192];      // 32 KB: Kh|Vh / post scratch / reduce
  const int b = blockIdx.x;
  const int t = threadIdx.x;       // 1024
  const int L0 = l0[b], L1 = l1[b], L2c = l2[b], L3 = l3[b];
  const int o1 = L0, o2 = L0 + L1, o3 = o2 + L2c, L = o3 + L3;

  // ---- phase P: ragged pack into xt ----
  {
    const int gi = t >> 5, ll = t & 31;
    for (int r = gi; r < L; r += 32) {
      int k, p;
      if (r < o1)      { k = 0; p = r; }
      else if (r < o2) { k = 1; p = r - o1; }
      else if (r < o3) { k = 2; p = r - o2; }
      else             { k = 3; p = r - o3; }
      const float* mas = (k == 0) ? m0 : (k == 1) ? m1 : (k == 2) ? m2 : m3;
      const float* mrow = mas + ((size_t)b * LSUB_ + p) * DD_;
      float v;
      if (ll < TD_ - 2) {
        float a = rb[ll];
        const float* w = rw + ll * DD_;
        for (int d = 0; d < DD_; ++d) a += mrow[d] * w[d];
        v = a;
      } else if (ll == TD_ - 2) {
        v = (k == 0 || k == 2) ? 1.f : 0.f;
      } else {
        v = (k < 2) ? 1.f : 0.f;
      }
      xt[r * 33 + ll] = v;
    }
  }
  __syncthreads();

  const int q = t >> 1, half = t & 1;          // query per lane-pair
  const float scale = 0.35355339059327373f;    // 1/sqrt(8)

  for (int li = 0; li < 2; ++li) {
    const float* wi = attn_in_w + (size_t)li * 96 * TD_;
    const float* bi = attn_in_b + (size_t)li * 96;
    float oacc[16];                            // [head][4] this thread's half
#pragma unroll
    for (int h = 0; h < NH_; ++h) {
      __syncthreads();                         // scr free (prev head/post)
      // stage Kh, Vh from xt
      for (int idx = t; idx < L * DH_; idx += 1024) {
        int p = idx >> 3, d = idx & 7;
        const float* wk = wi + (32 + h * 8 + d) * TD_;
        const float* wv = wi + (64 + h * 8 + d) * TD_;
        float ak = bi[32 + h * 8 + d], av = bi[64 + h * 8 + d];
        const float* xr = &xt[p * 33];
#pragma unroll
        for (int k = 0; k < TD_; ++k) { float x = xr[k]; ak += x * wk[k]; av += x * wv[k]; }
        scr[idx] = ak;
        scr[4096 + idx] = av;
      }
      __syncthreads();
      float lsum = 0.f;
      float a[8] = {0, 0, 0, 0, 0, 0, 0, 0};
      if (q < L) {
        float qv[8];
        const float* xr = &xt[q * 33];
#pragma unroll
        for (int d = 0; d < 8; ++d) {
          const float* wq = wi + (h * 8 + d) * TD_;
          float aq = bi[h * 8 + d];
#pragma unroll
          for (int k = 0; k < TD_; ++k) aq += xr[k] * wq[k];
          qv[d] = aq * scale;
        }
        for (int jj = half; jj < L; jj += 2) {
          const float* kr = &scr[jj * 8];
          float s = 0.f;
#pragma unroll
          for (int d = 0; d < 8; ++d) s += qv[d] * kr[d];
          float pr = __expf(s);
          lsum += pr;
          const float* vr = &scr[4096 + jj * 8];
#pragma unroll
          for (int d = 0; d < 8; ++d) a[d] += pr * vr[d];
        }
      }
      lsum += __shfl_xor(lsum, 1);
#pragma unroll
      for (int d = 0; d < 8; ++d) a[d] += __shfl_xor(a[d], 1);
      float inv = (q < L) ? 1.f / lsum : 0.f;
#pragma unroll
      for (int d = 0; d < 4; ++d) oacc[h * 4 + d] = a[half * 4 + d] * inv;
    }
    // ---- post: oproj + res + LN1 + FFN + res + LN2, 32-row chunks ----
    const float* ow = attn_out_w + (size_t)li * TD_ * TD_;
    const float* ob = attn_out_b + (size_t)li * TD_;
    const float* w1 = ff1_w + (size_t)li * DFF_ * TD_;
    const float* b1 = ff1_b + (size_t)li * DFF_;
    const float* w2 = ff2_w + (size_t)li * TD_ * DFF_;
    const float* b2 = ff2_b + (size_t)li * TD_;
    const float* A1 = ln1_w + (size_t)li * TD_;
    const float* B1 = ln1_b + (size_t)li * TD_;
    const float* A2 = ln2_w + (size_t)li * TD_;
    const float* B2 = ln2_b + (size_t)li * TD_;
    float* obufc = scr;             // [32][33]
    float* xsc   = scr + 32 * 33;   // [32][33]
    float* hbc   = scr + 64 * 33;   // [32][128]
    for (int c0 = 0; c0 < 512; c0 += 32) {
      if (c0 >= L) break;                       // block-uniform
      __syncthreads();                          // scr free (attn / prev chunk)
      if (q >= c0 && q < c0 + 32 && q < L) {
        int u = q - c0;
#pragma unroll
        for (int h2 = 0; h2 < 4; ++h2)
#pragma unroll
          for (int d = 0; d < 4; ++d)
            obufc[u * 33 + h2 * 8 + half * 4 + d] = oacc[h2 * 4 + d];
      }
      __syncthreads();
      {
        const int u = t >> 5, jj = t & 31;
        const int r = c0 + u;
        const bool alive = r < L;               // uniform per 32-lane group
        float a_ = 0.f;
        if (alive) {
          a_ = ob[jj] + xt[r * 33 + jj];
          const float* wr = ow + jj * TD_;
#pragma unroll
          for (int k = 0; k < TD_; ++k) a_ += obufc[u * 33 + k] * wr[k];
        }
        float s1 = a_, s2 = a_ * a_;
#pragma unroll
        for (int m = 1; m < 32; m <<= 1) {
          s1 += __shfl_xor(s1, m, 32);
          s2 += __shfl_xor(s2, m, 32);
        }
        if (alive) {
          float mean = s1 * (1.f / 32.f);
          float var  = s2 * (1.f / 32.f) - mean * mean;
          xsc[u * 33 + jj] = (a_ - mean) * rsqrtf(var + EPS_) * A1[jj] + B1[jj];
        }
      }
      __syncthreads();
      for (int idx = t; idx < 32 * DFF_; idx += 1024) {
        const int u = idx >> 7, jj = idx & 127;
        if (c0 + u < L) {
          float a_ = b1[jj];
          const float* wr = w1 + jj * TD_;
#pragma unroll
          for (int k = 0; k < TD_; ++k) a_ += xsc[u * 33 + k] * wr[k];
          hbc[u * 128 + jj] = fmaxf(a_, 0.f);
        }
      }
      __syncthreads();
      {
        const int u = t >> 5, jj = t & 31;
        const int r = c0 + u;
        const bool alive = r < L;
        float a_ = 0.f;
        if (alive) {
          a_ = b2[jj] + xsc[u * 33 + jj];
          const float* wr = w2 + jj * DFF_;
#pragma unroll
          for (int k = 0; k < DFF_; ++k) a_ += hbc[u * 128 + k] * wr[k];
        }
        float s1 = a_, s2 = a_ * a_;
#pragma unroll
        for (int m = 1; m < 32; m <<= 1) {
          s1 += __shfl_xor(s1, m, 32);
          s2 += __shfl_xor(s2, m, 32);
        }
        if (alive) {
          float mean = s1 * (1.f / 32.f);
          float var  = s2 * (1.f / 32.f) - mean * mean;
          xt[r * 33 + jj] = (a_ - mean) * rsqrtf(var + EPS_) * A2[jj] + B2[jj];
        }
      }
    }
    __syncthreads();                            // xt ready for next layer
  }

  // ---- fc phase: xf[256] = leaky(pooled.W/500 + b) for both graphs ----
  float* xf = scr + 1200;                       // [256]
  {
    const int g2 = t >> 9, rest = t & 511;
    const int o = rest >> 2, sub = t & 3;
    const float* pp = pooled + ((size_t)g2 * B_ + b) * F_;
    const float* wrow = (g2 ? fcw1 : fcw0) + (size_t)o * F_;
    float a = 0.f;
    for (int kk = 0; kk < 256; ++kk) {
      int k = sub * 256 + kk;
      a += pp[k] * wrow[k];
    }
    a += __shfl_xor(a, 1, 4);
    a += __shfl_xor(a, 2, 4);
    if (sub == 0)
      xf[g2 * 128 + o] = leaky(a * (1.f / 500.f) + (g2 ? fcb1 : fcb0)[o]);
  }
  // ---- masked mean over xt rows ----
  float* sb = scr;                              // [32][33] partials
  float* mo = scr + 1056;                       // [32]
  {
    const int c = t >> 5, jj = t & 31;
    float s = 0.f;
    for (int r = c; r < L; r += 32) s += xt[r * 33 + jj];
    sb[c * 33 + jj] = s;
  }
  __syncthreads();
  if (t < 32) {
    float a = 0.f;
#pragma unroll
    for (int c = 0; c < 32; ++c) a += sb[c * 33 + t];
    mo[t] = a / (float)L;
  }
  __syncthreads();
  // ---- final linear ----
  if (t < 64) {
    float s2 = 0.f;
    for (int i = t; i < 2 * OD_ + TD_; i += 64) {
      float cv = (i < 256) ? xf[i] : mo[i - 256];
      s2 += fw[i] * cv;
    }
#pragma unroll
    for (int m = 1; m < 64; m <<= 1) s2 += __shfl_xor(s2, m, 64);
    if (t == 0) out[b] = s2 + fb[0];
  }
}

extern "C" void kernel_launch(void* const* d_in, const int* in_sizes, int n_in,
                              void* d_out, int out_size, void* d_ws, size_t ws_size,
                              hipStream_t stream) {
  (void)in_sizes; (void)n_in; (void)out_size; (void)ws_size;
  const float* pro_x[2]  = {(const float*)d_in[0], (const float*)d_in[1]};
  const int*   pro_ei[2] = {(const int*)d_in[2], (const int*)d_in[3]};
  const float* mas[4]    = {(const float*)d_in[6], (const float*)d_in[8],
                            (const float*)d_in[10], (const float*)d_in[12]};
  const int*   lens[4]   = {(const int*)d_in[7], (const int*)d_in[9],
                            (const int*)d_in[11], (const int*)d_in[13]};
  const float* gw[2]  = {(const float*)d_in[14], (const float*)d_in[16]};
  const float* gb[2]  = {(const float*)d_in[15], (const float*)d_in[17]};
  const float* fcw[2] = {(const float*)d_in[18], (const float*)d_in[20]};
  const float* fcb[2] = {(const float*)d_in[19], (const float*)d_in[21]};
  const float* red_w = (const float*)d_in[22];
  const float* red_b = (const float*)d_in[23];
  const float* attn_in_w  = (const float*)d_in[24];
  const float* attn_in_b  = (const float*)d_in[25];
  const float* attn_out_w = (const float*)d_in[26];
  const float* attn_out_b = (const float*)d_in[27];
  const float* ln1_w = (const float*)d_in[28];
  const float* ln1_b = (const float*)d_in[29];
  const float* ln2_w = (const float*)d_in[30];
  const float* ln2_b = (const float*)d_in[31];
  const float* ff1_w = (const float*)d_in[32];
  const float* ff1_b = (const float*)d_in[33];
  const float* ff2_w = (const float*)d_in[34];
  const float* ff2_b = (const float*)d_in[35];
  const float* final_w = (const float*)d_in[36];
  const float* final_b = (const float*)d_in[37];
  float* out = (float*)d_out;

  char* p = (char*)d_ws;
  auto carve = [&](size_t bytes) -> void* {
    void* r = (void*)p;
    p += (bytes + 255) & ~(size_t)255;
    return r;
  };
  unsigned short* xb  = (unsigned short*)carve((size_t)2 * MPAD_ * F_ * 2);
  unsigned short* Wb  = (unsigned short*)carve((size_t)2 * F_ * F_ * 2);
  unsigned short* h   = (unsigned short*)carve((size_t)2 * MPAD_ * F_ * 2);
  int*   cnt      = (int*)carve((size_t)2 * N_NODES * 4);
  float* dinv     = (float*)carve((size_t)2 * N_NODES * 4);
  int*   rowstart = (int*)carve((size_t)2 * (N_NODES + 1) * 4);
  int*   cursor   = (int*)carve((size_t)2 * N_NODES * 4);
  int2*  csre     = (int2*)carve((size_t)2 * E_ * 8);
  float* pooled   = (float*)carve((size_t)2 * B_ * F_ * 4);

  // 1. prep: f2bf + zero cnt/pooled
  k_prep<<<dim3(1024, 5), 256, 0, stream>>>(pro_x[0], pro_x[1], gw[0], gw[1],
                                            xb, xb + (size_t)MPAD_ * F_,
                                            Wb, Wb + (size_t)F_ * F_, cnt, pooled);
  // 2. hist (before gemm so scan can ride in gemm)
  k_hist<<<dim3(1000, 2), 256, 0, stream>>>(pro_ei[0], pro_ei[1], cnt, E_, N_NODES);
  // 3. gemm + scan rider (block x==252 per graph)
  k_gemm256<<<dim3(253, 1, 2), 512, 0, stream>>>(xb, Wb, h, cnt, rowstart, cursor, dinv);
  // 4. scatter
  k_scatter<<<dim3(1000, 2), 256, 0, stream>>>(pro_ei[0], pro_ei[1], dinv, cursor,
                                               csre, E_, N_NODES);
  // 5. gather + fused mean-pool
  k_gather<<<dim3(8, 1000, 2), 256, 0, stream>>>((const uint4*)h, dinv, rowstart,
                                                 csre, gb[0], gb[1], pooled);
  // 6. former: pack + transformer x2 + masked-mean + fc + final
  k_former<<<B_, 1024, 0, stream>>>(mas[0], mas[1], mas[2], mas[3],
                                    lens[0], lens[1], lens[2], lens[3],
                                    red_w, red_b,
                                    attn_in_w, attn_in_b, attn_out_w, attn_out_b,
                                    ln1_w, ln1_b, ln2_w, ln2_b,
                                    ff1_w, ff1_b, ff2_w, ff2_b,
                                    pooled, fcw[0], fcw[1], fcb[0], fcb[1],
                                    final_w, final_b, out);
}